// Round 11
// baseline (799.091 us; speedup 1.0000x reference)
//
#include <hip/hip_runtime.h>

// SimpleRNN: x(256,2048,8) f32, h(1,256,128), W_ih(128,8), W_hh(128,128),
// b_ih(128), b_hh(128), W_head(1,128), b_head(1)
// out = [pred(256) | last_step_features(256,128) | h_n(256,128)]  (f32)
//
// R9: LDS-read-minimal decomposition + real register budget.
//  - R0-R8 post-mortem: 64 broadcast ds_read_b128/step/CU (J=128 j-groups)
//    ~= 768cy of LDS pipe == the measured step time. Inst count scales J/2.
//  - This kernel: J=32, K=8. 256 threads (4 waves, 1/SIMD). lane=(jg,kc),
//    lane computes 4 outputs j0..j0+3 over k-chunk kc*16..+15 using
//    v_pk_fma_f32 op_sel broadcast (R4-verified). 16 ds_read_b128/step/CU.
//  - amdgpu_waves_per_eu(1,1): RA budget 256 VGPR -> no remat pressure
//    (R8 proved "v"-consumption alone does not stop invariant-load remat).
//  - h stored bank-swizzled: chunk c (16 floats) at float offset 20c ->
//    8 kc chunks hit 8 distinct bank groups; b128 reads conflict-free.
//  - reduce over kc: 2 DPP quad stages + shfl_xor(4). f32 math (R3 numerics).

typedef float f32x2 __attribute__((ext_vector_type(2)));
typedef float f32x4 __attribute__((ext_vector_type(4)));

#define BB 256
#define TT 2048
#define II 8
#define HH 128
#define THREADS 256

// v_pk_fma_f32 with src0 LO/HI broadcast to both halves (R4-verified)
#define PK_FMA_LO(acc, hp, wp) \
    asm("v_pk_fma_f32 %0, %1, %2, %0 op_sel:[0,0,0] op_sel_hi:[0,1,1]" \
        : "+v"(acc) : "v"(hp), "v"(wp))
#define PK_FMA_HI(acc, hp, wp) \
    asm("v_pk_fma_f32 %0, %1, %2, %0 op_sel:[1,0,0] op_sel_hi:[1,1,1]" \
        : "+v"(acc) : "v"(hp), "v"(wp))

__device__ __forceinline__ float quad_sum(float x) {
    // xor1 + xor2 butterfly within each aligned quad (DPP)
    int xi = __builtin_bit_cast(int, x);
    int y1 = __builtin_amdgcn_update_dpp(0, xi, 0xB1, 0xF, 0xF, true); // [1,0,3,2]
    float s1 = x + __builtin_bit_cast(float, y1);
    int s1i = __builtin_bit_cast(int, s1);
    int y2 = __builtin_amdgcn_update_dpp(0, s1i, 0x4E, 0xF, 0xF, true); // [2,3,0,1]
    return s1 + __builtin_bit_cast(float, y2);
}

__global__ void
__launch_bounds__(THREADS, 1)
__attribute__((amdgpu_waves_per_eu(1, 1)))
rnn_v9_kernel(const float* __restrict__ x,
              const float* __restrict__ h0,
              const float* __restrict__ W_ih,
              const float* __restrict__ W_hh,
              const float* __restrict__ b_ih,
              const float* __restrict__ b_hh,
              const float* __restrict__ W_head,
              const float* __restrict__ b_head,
              float* __restrict__ out)
{
    // swizzled h: value j lives at [buf][ (j>>4)*20 + (j&15) ] (chunk pad 4)
    __shared__ __align__(16) float hswz[2][160];
    __shared__ __align__(16) float x_flat[2 * 16 * II];   // 256 floats
    __shared__ float part[HH];

    const int tid  = threadIdx.x;
    const int w    = tid >> 6;       // wave 0..3
    const int lane = tid & 63;
    const int jg   = lane >> 3;      // 0..7
    const int kc   = lane & 7;       // 0..7 (k-chunk of 16)
    const int j0   = w * 32 + jg * 4;  // 4 consecutive outputs
    const int b    = blockIdx.x;

    // ---- weights: wAB[k2]=(W[j0][k],W[j0+1][k]), wCD=(W[j0+2],W[j0+3]) ----
    f32x2 wAB[16], wCD[16];
    {
        const float* r0 = W_hh + (size_t)(j0 + 0) * HH + kc * 16;
        const float* r1 = W_hh + (size_t)(j0 + 1) * HH + kc * 16;
        const float* r2 = W_hh + (size_t)(j0 + 2) * HH + kc * 16;
        const float* r3 = W_hh + (size_t)(j0 + 3) * HH + kc * 16;
        #pragma unroll
        for (int k2 = 0; k2 < 16; ++k2) {
            wAB[k2] = (f32x2){r0[k2], r1[k2]};
            wCD[k2] = (f32x2){r2[k2], r3[k2]};
        }
    }
    // x-projection column kc (each kc group covers input i=kc)
    f32x2 wxAB = (f32x2){W_ih[(j0 + 0) * II + kc], W_ih[(j0 + 1) * II + kc]};
    f32x2 wxCD = (f32x2){W_ih[(j0 + 2) * II + kc], W_ih[(j0 + 3) * II + kc]};
    // bias carried by kc==0 lanes only
    f32x2 bAB = (kc == 0) ? (f32x2){b_ih[j0] + b_hh[j0], b_ih[j0+1] + b_hh[j0+1]}
                          : (f32x2){0.f, 0.f};
    f32x2 bCD = (kc == 0) ? (f32x2){b_ih[j0+2] + b_hh[j0+2], b_ih[j0+3] + b_hh[j0+3]}
                          : (f32x2){0.f, 0.f};

    // opaque pin (with waves_per_eu(1,1) budget the RA can simply keep them)
    asm volatile("" : "+v"(wAB[0]), "+v"(wAB[1]), "+v"(wAB[2]), "+v"(wAB[3]),
                      "+v"(wAB[4]), "+v"(wAB[5]), "+v"(wAB[6]), "+v"(wAB[7]),
                      "+v"(wAB[8]), "+v"(wAB[9]), "+v"(wAB[10]), "+v"(wAB[11]),
                      "+v"(wAB[12]), "+v"(wAB[13]), "+v"(wAB[14]), "+v"(wAB[15]));
    asm volatile("" : "+v"(wCD[0]), "+v"(wCD[1]), "+v"(wCD[2]), "+v"(wCD[3]),
                      "+v"(wCD[4]), "+v"(wCD[5]), "+v"(wCD[6]), "+v"(wCD[7]),
                      "+v"(wCD[8]), "+v"(wCD[9]), "+v"(wCD[10]), "+v"(wCD[11]),
                      "+v"(wCD[12]), "+v"(wCD[13]), "+v"(wCD[14]), "+v"(wCD[15]));
    asm volatile("" : "+v"(wxAB), "+v"(wxCD), "+v"(bAB), "+v"(bCD));

    const float* xg = x + (size_t)b * TT * II;

    if (tid < HH) {
        hswz[0][(tid >> 4) * 20 + (tid & 15)] = h0[b * HH + tid];
        x_flat[tid] = xg[tid];           // x for steps 0..15
    }
    __syncthreads();

    float xpre = 0.0f;

    for (int t = 0; t < TT; ++t) {
        const int tin = t & 15;
        const int rb  = t & 1;           // read buffer

        if (tid < HH) {
            if (tin == 0) {
                const int tn = t + 16;
                xpre = (tn < TT) ? xg[tn * II + tid] : 0.0f;   // coalesced
            }
        }

        // ---- x term + bias ----
        const float xs = x_flat[((t >> 4) & 1) * 128 + tin * II + kc];
        f32x2 xs2; xs2.x = xs; xs2.y = xs;
        f32x2 aAB = bAB, aCD = bCD;
        f32x2 aAB2 = (f32x2){0.f, 0.f}, aCD2 = (f32x2){0.f, 0.f};
        PK_FMA_LO(aAB, xs2, wxAB);
        PK_FMA_LO(aCD, xs2, wxCD);

        // ---- h chunk: 4 conflict-free b128 reads (chunk kc at float 20*kc) ----
        const float* hb = &hswz[rb][kc * 20];
        const f32x4 hq0 = *(const f32x4*)&hb[0];
        const f32x4 hq1 = *(const f32x4*)&hb[4];
        const f32x4 hq2 = *(const f32x4*)&hb[8];
        const f32x4 hq3 = *(const f32x4*)&hb[12];

        #define QBLK(hq, base, accAB, accCD)                                  \
        {                                                                     \
            const f32x2 h01 = __builtin_shufflevector(hq, hq, 0, 1);          \
            const f32x2 h23 = __builtin_shufflevector(hq, hq, 2, 3);          \
            PK_FMA_LO(accAB, h01, wAB[(base) + 0]);                           \
            PK_FMA_HI(accAB, h01, wAB[(base) + 1]);                           \
            PK_FMA_LO(accAB, h23, wAB[(base) + 2]);                           \
            PK_FMA_HI(accAB, h23, wAB[(base) + 3]);                           \
            PK_FMA_LO(accCD, h01, wCD[(base) + 0]);                           \
            PK_FMA_HI(accCD, h01, wCD[(base) + 1]);                           \
            PK_FMA_LO(accCD, h23, wCD[(base) + 2]);                           \
            PK_FMA_HI(accCD, h23, wCD[(base) + 3]);                           \
        }
        QBLK(hq0,  0, aAB,  aCD)
        QBLK(hq1,  4, aAB2, aCD2)
        QBLK(hq2,  8, aAB,  aCD)
        QBLK(hq3, 12, aAB2, aCD2)
        #undef QBLK

        const f32x2 sAB = aAB + aAB2;
        const f32x2 sCD = aCD + aCD2;

        // ---- reduce over kc: quad (xor1,xor2 DPP) then xor4 ----
        float s0 = quad_sum(sAB.x);
        float s1 = quad_sum(sAB.y);
        float s2 = quad_sum(sCD.x);
        float s3 = quad_sum(sCD.y);
        s0 += __shfl_xor(s0, 4);
        s1 += __shfl_xor(s1, 4);
        s2 += __shfl_xor(s2, 4);
        s3 += __shfl_xor(s3, 4);

        // ---- tanh x4 ----
        const float e0 = __builtin_amdgcn_exp2f(s0 * 2.8853900817779268f);
        const float e1 = __builtin_amdgcn_exp2f(s1 * 2.8853900817779268f);
        const float e2 = __builtin_amdgcn_exp2f(s2 * 2.8853900817779268f);
        const float e3 = __builtin_amdgcn_exp2f(s3 * 2.8853900817779268f);
        f32x4 th;
        th.x = 1.0f - 2.0f * __builtin_amdgcn_rcpf(e0 + 1.0f);
        th.y = 1.0f - 2.0f * __builtin_amdgcn_rcpf(e1 + 1.0f);
        th.z = 1.0f - 2.0f * __builtin_amdgcn_rcpf(e2 + 1.0f);
        th.w = 1.0f - 2.0f * __builtin_amdgcn_rcpf(e3 + 1.0f);

        // ---- h write: kc==0 lanes, one b128 each (swizzled, conflict-free) ----
        if (kc == 0)
            *(f32x4*)&hswz[rb ^ 1][(j0 >> 4) * 20 + (j0 & 15)] = th;

        if (tid < HH) {
            if (tin == 15) x_flat[(((t >> 4) + 1) & 1) * 128 + tid] = xpre;
        }

        // ONE barrier per step; lgkm only -- x prefetch floats across
        asm volatile("s_waitcnt lgkmcnt(0)\n\ts_barrier" ::: "memory");
    }

    // ---- epilogue: final h in hswz[0] (t=2047: rb=1, wrote buf 0) ----
    __syncthreads();
    if (tid < HH) {
        const float hl = hswz[0][(tid >> 4) * 20 + (tid & 15)];
        out[BB + b * HH + tid]           = hl;   // last_step_features
        out[BB + BB * HH + b * HH + tid] = hl;   // h_n
        part[tid] = hl * W_head[tid];
    }
    __syncthreads();
    if (w == 0) {
        float s = part[lane] + part[lane + 64];
        #pragma unroll
        for (int off = 32; off > 0; off >>= 1) s += __shfl_down(s, off);
        if (lane == 0) out[b] = s + b_head[0];
    }
}

extern "C" void kernel_launch(void* const* d_in, const int* in_sizes, int n_in,
                              void* d_out, int out_size, void* d_ws, size_t ws_size,
                              hipStream_t stream) {
    const float* x      = (const float*)d_in[0];
    const float* h0     = (const float*)d_in[1];
    const float* W_ih   = (const float*)d_in[2];
    const float* W_hh   = (const float*)d_in[3];
    const float* b_ih   = (const float*)d_in[4];
    const float* b_hh   = (const float*)d_in[5];
    const float* W_head = (const float*)d_in[6];
    const float* b_head = (const float*)d_in[7];
    float* out = (float*)d_out;

    hipLaunchKernelGGL(rnn_v9_kernel, dim3(BB), dim3(THREADS), 0, stream,
                       x, h0, W_ih, W_hh, b_ih, b_hh, W_head, b_head, out);
}

// Round 12
// 576.371 us; speedup vs baseline: 1.3864x; 1.3864x over previous
//
#include <hip/hip_runtime.h>

// SimpleRNN: x(256,2048,8) f32, h(1,256,128), W_ih(128,8), W_hh(128,128),
// b_ih(128), b_hh(128), W_head(1,128), b_head(1)
// out = [pred(256) | last_step_features(256,128) | h_n(256,128)]  (f32)
//
// R10: latency-segment-minimal variant of R3 (best: 649us).
//  - 4 waves (1/SIMD), 256 thr: lane=(jg 0..15, kc 0..3), 2 outputs/lane via
//    v_pk_fma_f32 op_sel broadcast (R4-verified). Halves barrier skew and
//    LDS read volume vs R3's 8 waves.
//  - reduce: pure quad-DPP (2 stages). NO shfl_xor/ds_bpermute (R9's mistake).
//  - raw s_barrier + lgkmcnt(0) only: no vmcnt drain (R3 paid an HBM-latency
//    x-prefetch inside __syncthreads every 16th step).
//  - x read DIRECT from global per step (L2-resident 64KB/block), 2-step
//    register pipeline; x_flat LDS staging deleted.
//  - weights re-fetch (remat) accepted: R9 proved no pinning idiom stops it.

typedef float f32x2 __attribute__((ext_vector_type(2)));
typedef float f32x4 __attribute__((ext_vector_type(4)));

#define BB 256
#define TT 2048
#define II 8
#define HH 128
#define THREADS 256

// v_pk_fma_f32, src0 LO/HI broadcast to both halves (R4-verified encodings)
#define PK_FMA_LO(acc, hp, wp) \
    asm("v_pk_fma_f32 %0, %1, %2, %0 op_sel:[0,0,0] op_sel_hi:[0,1,1]" \
        : "+v"(acc) : "v"(hp), "v"(wp))
#define PK_FMA_HI(acc, hp, wp) \
    asm("v_pk_fma_f32 %0, %1, %2, %0 op_sel:[1,0,0] op_sel_hi:[1,1,1]" \
        : "+v"(acc) : "v"(hp), "v"(wp))

__device__ __forceinline__ float quad_sum(float x) {
    // xor1 + xor2 butterfly within each aligned 4-lane quad (DPP only)
    int xi = __builtin_bit_cast(int, x);
    int y1 = __builtin_amdgcn_update_dpp(0, xi, 0xB1, 0xF, 0xF, true); // [1,0,3,2]
    float s1 = x + __builtin_bit_cast(float, y1);
    int s1i = __builtin_bit_cast(int, s1);
    int y2 = __builtin_amdgcn_update_dpp(0, s1i, 0x4E, 0xF, 0xF, true); // [2,3,0,1]
    return s1 + __builtin_bit_cast(float, y2);
}

__launch_bounds__(THREADS, 1)
__global__ void rnn_v10_kernel(const float* __restrict__ x,
                               const float* __restrict__ h0,
                               const float* __restrict__ W_ih,
                               const float* __restrict__ W_hh,
                               const float* __restrict__ b_ih,
                               const float* __restrict__ b_hh,
                               const float* __restrict__ W_head,
                               const float* __restrict__ b_head,
                               float* __restrict__ out)
{
    __shared__ __align__(16) float h_lds[2][HH];   // ping-pong hidden state
    __shared__ float part[HH];

    const int b    = blockIdx.x;
    const int tid  = threadIdx.x;
    const int w    = tid >> 6;        // wave 0..3
    const int lane = tid & 63;
    const int jg   = lane >> 2;       // 0..15
    const int kc   = lane & 3;        // 0..3 (32-k chunk)
    const int j0   = w * 32 + jg * 2; // this lane's 2 outputs: j0, j0+1

    // ---- weights in READ order (rotation (i+2kc)&7 baked into slot index):
    // wj[4i+c] = (W_hh[j0][kc*32+4m+c], W_hh[j0+1][kc*32+4m+c]), m=(i+2kc)&7
    f32x2 wj[32];
    {
        const float* r0 = W_hh + (size_t)j0 * HH + kc * 32;
        const float* r1 = r0 + HH;
        #pragma unroll
        for (int i = 0; i < 8; ++i) {
            const int m = (i + 2 * kc) & 7;
            #pragma unroll
            for (int c = 0; c < 4; ++c)
                wj[4 * i + c] = (f32x2){r0[4 * m + c], r1[4 * m + c]};
        }
    }
    f32x2 wx0 = (f32x2){W_ih[j0 * II + 2 * kc],     W_ih[(j0 + 1) * II + 2 * kc]};
    f32x2 wx1 = (f32x2){W_ih[j0 * II + 2 * kc + 1], W_ih[(j0 + 1) * II + 2 * kc + 1]};
    f32x2 bias2 = (f32x2){0.25f * (b_ih[j0] + b_hh[j0]),
                          0.25f * (b_ih[j0 + 1] + b_hh[j0 + 1])};

    if (tid < HH) h_lds[0][tid] = h0[b * HH + tid];
    __syncthreads();

    // x: direct global reads, 2-step register pipeline (L2-resident, vmcnt
    // never drained in-loop so these float across barriers)
    const float* xk = x + (size_t)b * TT * II + 2 * kc;
    f32x2 xe = *(const f32x2*)(xk + 0 * II);
    f32x2 xo = *(const f32x2*)(xk + 1 * II);

    #define STEP(XV, RBUF, TN)                                                   \
    {                                                                            \
        f32x2 a0 = bias2;                                                        \
        f32x2 a1 = (f32x2){0.f, 0.f};                                            \
        f32x2 a2 = (f32x2){0.f, 0.f};                                            \
        f32x2 a3 = (f32x2){0.f, 0.f};                                            \
        PK_FMA_LO(a0, XV, wx0);          /* x[2kc]   * W_ih col for j0,j1 */     \
        PK_FMA_HI(a1, XV, wx1);          /* x[2kc+1] * W_ih col for j0,j1 */     \
        _Pragma("unroll")                                                        \
        for (int i = 0; i < 8; i += 2) {                                         \
            const f32x4 hva = *(const f32x4*)                                    \
                &h_lds[RBUF][kc * 32 + (((i + 0) + 2 * kc) & 7) * 4];            \
            const f32x4 hvb = *(const f32x4*)                                    \
                &h_lds[RBUF][kc * 32 + (((i + 1) + 2 * kc) & 7) * 4];            \
            const f32x2 ha01 = __builtin_shufflevector(hva, hva, 0, 1);          \
            const f32x2 ha23 = __builtin_shufflevector(hva, hva, 2, 3);          \
            const f32x2 hb01 = __builtin_shufflevector(hvb, hvb, 0, 1);          \
            const f32x2 hb23 = __builtin_shufflevector(hvb, hvb, 2, 3);          \
            PK_FMA_LO(a0, ha01, wj[4 * i + 0]);                                  \
            PK_FMA_HI(a1, ha01, wj[4 * i + 1]);                                  \
            PK_FMA_LO(a2, ha23, wj[4 * i + 2]);                                  \
            PK_FMA_HI(a3, ha23, wj[4 * i + 3]);                                  \
            PK_FMA_LO(a0, hb01, wj[4 * i + 4]);                                  \
            PK_FMA_HI(a1, hb01, wj[4 * i + 5]);                                  \
            PK_FMA_LO(a2, hb23, wj[4 * i + 6]);                                  \
            PK_FMA_HI(a3, hb23, wj[4 * i + 7]);                                  \
        }                                                                        \
        const f32x2 s2 = (a0 + a1) + (a2 + a3);   /* v_pk_add_f32 x3 */          \
        const float s0 = quad_sum(s2.x);                                         \
        const float s1 = quad_sum(s2.y);                                         \
        const float e0 = __builtin_amdgcn_exp2f(s0 * 2.8853900817779268f);       \
        const float e1 = __builtin_amdgcn_exp2f(s1 * 2.8853900817779268f);       \
        f32x2 hn;                                                                \
        hn.x = 1.0f - 2.0f * __builtin_amdgcn_rcpf(e0 + 1.0f);                   \
        hn.y = 1.0f - 2.0f * __builtin_amdgcn_rcpf(e1 + 1.0f);                   \
        if (kc == 0) *(f32x2*)&h_lds[(RBUF) ^ 1][j0] = hn;                       \
        { const int tn_ = (TN) < TT ? (TN) : (TT - 1);                           \
          XV = *(const f32x2*)(xk + (size_t)tn_ * II); }                         \
        asm volatile("s_waitcnt lgkmcnt(0)\n\ts_barrier" ::: "memory");          \
    }

    for (int t = 0; t < TT; t += 2) {
        STEP(xe, 0, t + 2)   // even step: reads buf0, writes buf1
        STEP(xo, 1, t + 3)   // odd  step: reads buf1, writes buf0
    }
    #undef STEP

    // ---- epilogue: final h in h_lds[0] (t=2047 odd wrote buf 0) ----
    if (tid < HH) {
        const float hl = h_lds[0][tid];
        out[BB + b * HH + tid]           = hl;   // last_step_features
        out[BB + BB * HH + b * HH + tid] = hl;   // h_n
        part[tid] = hl * W_head[tid];
    }
    __syncthreads();
    if (w == 0) {
        float s = part[lane] + part[lane + 64];
        #pragma unroll
        for (int off = 32; off > 0; off >>= 1) s += __shfl_down(s, off);
        if (lane == 0) out[b] = s + b_head[0];
    }
}

extern "C" void kernel_launch(void* const* d_in, const int* in_sizes, int n_in,
                              void* d_out, int out_size, void* d_ws, size_t ws_size,
                              hipStream_t stream) {
    const float* x      = (const float*)d_in[0];
    const float* h0     = (const float*)d_in[1];
    const float* W_ih   = (const float*)d_in[2];
    const float* W_hh   = (const float*)d_in[3];
    const float* b_ih   = (const float*)d_in[4];
    const float* b_hh   = (const float*)d_in[5];
    const float* W_head = (const float*)d_in[6];
    const float* b_head = (const float*)d_in[7];
    float* out = (float*)d_out;

    hipLaunchKernelGGL(rnn_v10_kernel, dim3(BB), dim3(THREADS), 0, stream,
                       x, h0, W_ih, W_hh, b_ih, b_hh, W_head, b_head, out);
}